// Round 8
// baseline (382.999 us; speedup 1.0000x reference)
//
#include <hip/hip_runtime.h>

// out[s][o] = sum_i x[s][i] * dq(w[o][i]); int4 group quant, group=256, scale=max(absmax/7,1e-9)
// x: [16,4096] f32, w: [14336,4096] f32 (235 MB streamed once), out: [16,14336] f32
//
// R9 = R8 with the occupancy cap lifted (resubmitted x2 — R6 hit
// GPUAcquisitionTimeout, R7 hit "container failed twice"; never measured).
// R8 post-mortem: spill fixed as predicted (WRITE 263MB->1.3MB, VGPR 128->52)
// but kernel = 156 us, NOT 40-55. Counters: HBM 9.7% (FETCH only 117 MB — w is
// L3-resident across dispatches), VALU 61%, LDS-conflicts 0, Occupancy 34%
// (~11 waves/CU). Nothing saturated -> latency-bound at low occupancy.
// With VGPR=52 the register file is no longer the limiter; the 64 KB xs LDS
// buffer is: floor(160/64) = 2 blocks/CU = 14 waves.
// Fix: PH_I 1024 -> 512 (xs = 32 KB) -> residency min(floor(160/32)=5,
// floor(32/7)=4) = 4 blocks/CU = 28 waves. 8 staging phases instead of 4;
// with 4 independent blocks/CU the extra barriers overlap across blocks.
// Held fixed from R8 (all verified): RPW=2, depth-2 consume-at-top w
// prefetch, '#pragma unroll 1' on the g-loop (R7's full unroll -> 263 MB
// scratch spill; do not unroll).

constexpr int O_DIM  = 14336;
constexpr int I_DIM  = 4096;
constexpr int S_DIM  = 16;
constexpr int GS     = 256;           // quant group size
constexpr int NG     = I_DIM / GS;    // 16 groups
constexpr int RPW    = 2;             // rows per wave
constexpr int NWAVE  = 7;             // waves per block
constexpr int NTHR   = 64 * NWAVE;    // 448
constexpr int RPB    = RPW * NWAVE;   // 14 rows/block -> 1024 blocks
constexpr int PH_I   = 512;           // i-extent per x staging phase (32 KB LDS)
constexpr int NPH    = I_DIM / PH_I;  // 8 phases
constexpr int GPP    = PH_I / GS;     // 2 groups per phase
constexpr int SLOTS  = PH_I / 4;      // float4 slots per xs row (128)

// wave64 max-reduce on the VALU pipe (validated correct in R5..R8 runs):
// 4x row_shr + row_bcast15 + row_bcast31, readlane(63) -> wave-uniform SGPR.
// Inputs >= 0, so bound_ctrl=true zero-fill is identity for max.
__device__ __forceinline__ float wave_max_dpp(float x) {
    int v = __float_as_int(x);
    int t;
    t = __builtin_amdgcn_update_dpp(0, v, 0x111, 0xf, 0xf, true); // row_shr:1
    v = __float_as_int(fmaxf(__int_as_float(v), __int_as_float(t)));
    t = __builtin_amdgcn_update_dpp(0, v, 0x112, 0xf, 0xf, true); // row_shr:2
    v = __float_as_int(fmaxf(__int_as_float(v), __int_as_float(t)));
    t = __builtin_amdgcn_update_dpp(0, v, 0x114, 0xf, 0xf, true); // row_shr:4
    v = __float_as_int(fmaxf(__int_as_float(v), __int_as_float(t)));
    t = __builtin_amdgcn_update_dpp(0, v, 0x118, 0xf, 0xf, true); // row_shr:8
    v = __float_as_int(fmaxf(__int_as_float(v), __int_as_float(t)));
    t = __builtin_amdgcn_update_dpp(0, v, 0x142, 0xf, 0xf, true); // row_bcast:15
    v = __float_as_int(fmaxf(__int_as_float(v), __int_as_float(t)));
    t = __builtin_amdgcn_update_dpp(0, v, 0x143, 0xf, 0xf, true); // row_bcast:31
    v = __float_as_int(fmaxf(__int_as_float(v), __int_as_float(t)));
    return __int_as_float(__builtin_amdgcn_readlane(v, 63));
}

__global__ __launch_bounds__(NTHR)
void qlin_kernel(const float* __restrict__ x,
                 const float* __restrict__ w,
                 float* __restrict__ out)
{
    __shared__ float xs[S_DIM][PH_I];   // 32 KB -> LDS allows 4+ blocks/CU

    const int tid  = threadIdx.x;
    const int lane = tid & 63;
    const int wv   = tid >> 6;          // 0..6
    const int row0 = blockIdx.x * RPB + wv * RPW;

    const float* wp = w + (size_t)row0 * I_DIM + lane * 4;

    float acc[RPW][S_DIM];
#pragma unroll
    for (int r = 0; r < RPW; ++r)
#pragma unroll
        for (int s = 0; s < S_DIM; ++s) acc[r][s] = 0.0f;

    // depth-2 prefetch pipeline: wn1 holds group G, wn2 holds group G+1.
    float4 wcur[RPW], wn1[RPW], wn2[RPW];
#pragma unroll
    for (int r = 0; r < RPW; ++r)
        wn1[r] = *reinterpret_cast<const float4*>(wp + (size_t)r * I_DIM);
#pragma unroll
    for (int r = 0; r < RPW; ++r)
        wn2[r] = *reinterpret_cast<const float4*>(wp + (size_t)r * I_DIM + GS);

    for (int p = 0; p < NPH; ++p) {
        // ---- stage x[:, p*PH_I .. +PH_I) into LDS (2048 float4 / 448 thr) ----
        // reg-roundtrip staging (proven correct; avoids global_load_lds
        // masked-lane edge semantics on the non-divisible tail).
        if (p) __syncthreads();         // all waves done reading phase p-1
        for (int j = tid; j < S_DIM * SLOTS; j += NTHR) {
            const int s  = j / SLOTS;               // xs row
            const int i4 = (j % SLOTS) * 4;         // float4 offset in row
            *reinterpret_cast<float4*>(&xs[s][i4]) =
                *reinterpret_cast<const float4*>(
                    &x[(size_t)s * I_DIM + p * PH_I + i4]);
        }
        __syncthreads();

        // unroll 1: R7's full unroll here hoisted 4 iterations of loads and
        // blew past the 128-VGPR cap -> 263 MB of scratch spill. Do not unroll.
#pragma unroll 1
        for (int g = 0; g < GPP; ++g) {
            const int G = p * GPP + g;      // global group index

            // rotate the pipeline: consume oldest at the TOP of the iteration.
            // wn1's loads were issued 2 iterations ago -> vmcnt wait is ~free.
#pragma unroll
            for (int r = 0; r < RPW; ++r) { wcur[r] = wn1[r]; wn1[r] = wn2[r]; }

            // issue loads for G+2 — they have this iteration AND the next
            // (plus any barrier overlap) before their wait.
            if (G + 2 < NG) {
#pragma unroll
                for (int r = 0; r < RPW; ++r)
                    wn2[r] = *reinterpret_cast<const float4*>(
                        wp + (size_t)r * I_DIM + (G + 2) * GS);
            }

            // dequant wcur in place; absmax on VALU pipe via DPP
#pragma unroll
            for (int r = 0; r < RPW; ++r) {
                float4 v = wcur[r];
                float m = fmaxf(fmaxf(fabsf(v.x), fabsf(v.y)),
                                fmaxf(fabsf(v.z), fabsf(v.w)));
                m = wave_max_dpp(m);
                float scale = fmaxf(m * (1.0f / 7.0f), 1e-9f);
                float invs  = 1.0f / scale;
                // clamp provably dead: scale >= absmax/7 => |v*invs| <= 7
                wcur[r].x = rintf(v.x * invs) * scale;
                wcur[r].y = rintf(v.y * invs) * scale;
                wcur[r].z = rintf(v.z * invs) * scale;
                wcur[r].w = rintf(v.w * invs) * scale;
            }

            // FMA: x from LDS (lgkmcnt only — never waits on the w prefetch)
            const int xb = g * GS + lane * 4;
#pragma unroll
            for (int s = 0; s < S_DIM; ++s) {
                float4 xv = *reinterpret_cast<const float4*>(&xs[s][xb]);
#pragma unroll
                for (int r = 0; r < RPW; ++r) {
                    acc[r][s] = fmaf(wcur[r].x, xv.x, acc[r][s]);
                    acc[r][s] = fmaf(wcur[r].y, xv.y, acc[r][s]);
                    acc[r][s] = fmaf(wcur[r].z, xv.z, acc[r][s]);
                    acc[r][s] = fmaf(wcur[r].w, xv.w, acc[r][s]);
                }
            }
        }
    }

    // ---- epilogue: reduce 32 accs across 64 lanes ----
    // step 1: fold the two 32-lane halves (lanes l and l^32 hold the same
    //         index set) — 32 plain xor-adds.
    // step 2: value-splitting butterfly over 32 slots; lane l (l<32) ends
    //         with the sum of a[l], l = (r<<4)|s.
    float a[RPW * S_DIM];
#pragma unroll
    for (int r = 0; r < RPW; ++r)
#pragma unroll
        for (int s = 0; s < S_DIM; ++s) a[(r << 4) | s] = acc[r][s];

#pragma unroll
    for (int j = 0; j < RPW * S_DIM; ++j)
        a[j] += __shfl_xor(a[j], 32, 64);

#pragma unroll
    for (int m = 16; m >= 1; m >>= 1) {
        const bool hi = (lane & m) != 0;
#pragma unroll
        for (int j = 0; j < m; ++j) {
            float snd  = hi ? a[j] : a[j + m];
            float rcv  = __shfl_xor(snd, m, 64);
            float kept = hi ? a[j + m] : a[j];
            a[j] = kept + rcv;
        }
    }
    if (lane < 32) {
        const int r = (lane >> 4) & 1, s = lane & 15;
        out[s * O_DIM + (row0 + r)] = a[0];
    }
}

extern "C" void kernel_launch(void* const* d_in, const int* in_sizes, int n_in,
                              void* d_out, int out_size, void* d_ws, size_t ws_size,
                              hipStream_t stream) {
    const float* x = (const float*)d_in[0];   // 1*16*4096
    const float* w = (const float*)d_in[1];   // 14336*4096
    float* out = (float*)d_out;               // 16*14336
    dim3 grid(O_DIM / RPB);                   // 1024 blocks -> 4/CU resident
    dim3 block(NTHR);                         // 448 = 7 waves
    qlin_kernel<<<grid, block, 0, stream>>>(x, w, out);
}

// Round 9
// 363.882 us; speedup vs baseline: 1.0525x; 1.0525x over previous
//
#include <hip/hip_runtime.h>

// out[s][o] = sum_i x[s][i] * dq(w[o][i]); int4 group quant, group=256, scale=max(absmax/7,1e-9)
// x: [16,4096] f32, w: [14336,4096] f32 (235 MB streamed once), out: [16,14336] f32
//
// R10 = structural experiment: NO LDS, NO barriers.
// Evidence to date (kernel dispatch times): R6 RPW=4+LDS ~117us; R8 RPW=2
// 64KB 156us; R9 RPW=2 32KB 164us (halving LDS left Occupancy at 34% and made
// things WORSE -> occupancy/LDS-residency theory dead). All variants sit 3-4x
// above pipe floors (VALU ~20us, DS ~18-36us, HBM ~35us) and the derived
// counters are inconsistent with instruction counts (gfx94x fallback formulas)
// -> localize by construction instead: remove the only structural overheads
// every slow variant shares:
//  - __syncthreads() pairs per phase (each drains vmcnt(0)/lgkmcnt(0) for ALL
//    waves -> kills w-prefetch at every phase boundary, couples 7 waves to the
//    slowest straggler),
//  - the x LDS round-trip (global->reg->LDS write->LDS read).
// x is 256 KB: L2-resident (4MB/XCD); each group's 16 KB slice fits L1. Read
// x straight from global in the FMA loop (16 dwordx4/iter, L1/L2 hits),
// waves fully independent.
// Kept: RPW=4 (measured-best: amortizes x-reads+dequant over 2x FMAs),
// '#pragma unroll 1' on the G-loop (R7: full unroll -> 263MB scratch spill),
// DPP absmax (validated R5..R9), 64-slot value-split epilogue (validated R6).
// Dropped: w-prefetch double-buffer (keeps VGPR ~ acc64+w16+xv+addr ~110<128;
// w-load stall overlaps across ~16 independent waves/CU instead).
// Watch: WRITE_SIZE must stay ~1.3MB (spill tripwire); LDS_Block_Size -> 0.

constexpr int O_DIM  = 14336;
constexpr int I_DIM  = 4096;
constexpr int S_DIM  = 16;
constexpr int GS     = 256;           // quant group size
constexpr int NG     = I_DIM / GS;    // 16 groups
constexpr int RPW    = 4;             // rows per wave
constexpr int NWAVE  = 4;             // waves per block (no coupling — any value works)
constexpr int NTHR   = 64 * NWAVE;    // 256
constexpr int RPB    = RPW * NWAVE;   // 16 rows/block -> 896 blocks

// wave64 max-reduce on the VALU pipe (validated correct in R5..R9 runs):
// 4x row_shr + row_bcast15 + row_bcast31, readlane(63) -> wave-uniform SGPR.
// Inputs >= 0, so bound_ctrl=true zero-fill is identity for max.
__device__ __forceinline__ float wave_max_dpp(float x) {
    int v = __float_as_int(x);
    int t;
    t = __builtin_amdgcn_update_dpp(0, v, 0x111, 0xf, 0xf, true); // row_shr:1
    v = __float_as_int(fmaxf(__int_as_float(v), __int_as_float(t)));
    t = __builtin_amdgcn_update_dpp(0, v, 0x112, 0xf, 0xf, true); // row_shr:2
    v = __float_as_int(fmaxf(__int_as_float(v), __int_as_float(t)));
    t = __builtin_amdgcn_update_dpp(0, v, 0x114, 0xf, 0xf, true); // row_shr:4
    v = __float_as_int(fmaxf(__int_as_float(v), __int_as_float(t)));
    t = __builtin_amdgcn_update_dpp(0, v, 0x118, 0xf, 0xf, true); // row_shr:8
    v = __float_as_int(fmaxf(__int_as_float(v), __int_as_float(t)));
    t = __builtin_amdgcn_update_dpp(0, v, 0x142, 0xf, 0xf, true); // row_bcast:15
    v = __float_as_int(fmaxf(__int_as_float(v), __int_as_float(t)));
    t = __builtin_amdgcn_update_dpp(0, v, 0x143, 0xf, 0xf, true); // row_bcast:31
    v = __float_as_int(fmaxf(__int_as_float(v), __int_as_float(t)));
    return __int_as_float(__builtin_amdgcn_readlane(v, 63));
}

__global__ __launch_bounds__(NTHR)
void qlin_kernel(const float* __restrict__ x,
                 const float* __restrict__ w,
                 float* __restrict__ out)
{
    const int tid  = threadIdx.x;
    const int lane = tid & 63;
    const int wv   = tid >> 6;          // 0..NWAVE-1
    const int row0 = blockIdx.x * RPB + wv * RPW;

    const float* wp = w + (size_t)row0 * I_DIM + lane * 4;
    const float* xp = x + lane * 4;     // + s*I_DIM + G*GS per use

    float acc[RPW][S_DIM];
#pragma unroll
    for (int r = 0; r < RPW; ++r)
#pragma unroll
        for (int s = 0; s < S_DIM; ++s) acc[r][s] = 0.0f;

    // unroll 1: R7 lesson — cross-iteration hoisting of global loads blew the
    // 128-VGPR cap -> 263 MB scratch spill. Keep the loop body pinned.
#pragma unroll 1
    for (int G = 0; G < NG; ++G) {
        // w for this group: 4 coalesced dwordx4 per wave (the HBM stream).
        float4 wq[RPW];
#pragma unroll
        for (int r = 0; r < RPW; ++r)
            wq[r] = *reinterpret_cast<const float4*>(
                wp + (size_t)r * I_DIM + G * GS);

        // dequant in place; absmax on VALU pipe via DPP. The serial DPP chain
        // also gives the scheduler room to batch the upcoming x loads.
#pragma unroll
        for (int r = 0; r < RPW; ++r) {
            float4 v = wq[r];
            float m = fmaxf(fmaxf(fabsf(v.x), fabsf(v.y)),
                            fmaxf(fabsf(v.z), fabsf(v.w)));
            m = wave_max_dpp(m);
            float scale = fmaxf(m * (1.0f / 7.0f), 1e-9f);
            float invs  = 1.0f / scale;
            // clamp provably dead: scale >= absmax/7 => |v*invs| <= 7
            wq[r].x = rintf(v.x * invs) * scale;
            wq[r].y = rintf(v.y * invs) * scale;
            wq[r].z = rintf(v.z * invs) * scale;
            wq[r].w = rintf(v.w * invs) * scale;
        }

        // FMA: x straight from global (L1/L2-hit; x slice per group = 16 KB,
        // L1-resident; whole x = 256 KB, L2-resident). 16 dwordx4 per iter.
        const float* xg = xp + G * GS;
#pragma unroll
        for (int s = 0; s < S_DIM; ++s) {
            float4 xv = *reinterpret_cast<const float4*>(
                &xg[(size_t)s * I_DIM]);
#pragma unroll
            for (int r = 0; r < RPW; ++r) {
                acc[r][s] = fmaf(wq[r].x, xv.x, acc[r][s]);
                acc[r][s] = fmaf(wq[r].y, xv.y, acc[r][s]);
                acc[r][s] = fmaf(wq[r].z, xv.z, acc[r][s]);
                acc[r][s] = fmaf(wq[r].w, xv.w, acc[r][s]);
            }
        }
    }

    // ---- epilogue: reduce 64 accs across 64 lanes in 63 shuffles ----
    // value-splitting butterfly (validated in R6's passing run); lane l ends
    // with the sum of a[l], l = (r<<4)|s.
    float a[64];
#pragma unroll
    for (int r = 0; r < RPW; ++r)
#pragma unroll
        for (int s = 0; s < S_DIM; ++s) a[(r << 4) | s] = acc[r][s];

#pragma unroll
    for (int m = 32; m >= 1; m >>= 1) {
        const bool hi = (lane & m) != 0;
#pragma unroll
        for (int j = 0; j < m; ++j) {
            float snd  = hi ? a[j] : a[j + m];
            float rcv  = __shfl_xor(snd, m, 64);
            float kept = hi ? a[j + m] : a[j];
            a[j] = kept + rcv;
        }
    }
    {
        const int r = lane >> 4, s = lane & 15;
        out[s * O_DIM + (row0 + r)] = a[0];
    }
}

extern "C" void kernel_launch(void* const* d_in, const int* in_sizes, int n_in,
                              void* d_out, int out_size, void* d_ws, size_t ws_size,
                              hipStream_t stream) {
    const float* x = (const float*)d_in[0];   // 1*16*4096
    const float* w = (const float*)d_in[1];   // 14336*4096
    float* out = (float*)d_out;               // 16*14336
    dim3 grid(O_DIM / RPB);                   // 896 blocks
    dim3 block(NTHR);                         // 256 = 4 waves
    qlin_kernel<<<grid, block, 0, stream>>>(x, w, out);
}